// Round 10
// baseline (158.818 us; speedup 1.0000x reference)
//
#include <hip/hip_runtime.h>
#include <math.h>

#define Wd 256
#define Hd 256
#define KW 11
#define OUT_R 26              // output rows per block; stream 36 = 9 steps x 4 rows
#define BLOCK 384             // 6 independent waves
#define NW 6
#define OC 48                 // output cols per wave

typedef float v4f __attribute__((ext_vector_type(4)));

__device__ __forceinline__ float rfl(float v) {
    return __int_as_float(__builtin_amdgcn_readfirstlane(__float_as_int(v)));
}

// R10: WAVE-INDEPENDENT STREAMING -- zero barriers in the hot loop.
//
// Ledger (~42us invariant): barrier flavor (R2), residency supply (R4),
// prefetch depth (R5 -4%), skew (R6), step size/LDS layout (R7), bank
// conflicts (1.29M: no effect), memory residency (L3==HBM), instruction
// count (R9: pk_fma cut inst 35%, dur WORSE 76us -- pk fp32 is not
// double-rate, and VALU-busy time was unchanged). Pipe arithmetic:
// VALU-issue ~20us/CU + LDS ~18us/CU == measured 42us: the pipes SUM,
// never overlap. Shared property of all variants: waves of a block are
// barrier-locked into the same phase (convoy). This round removes the
// convoy: each wave owns a private 48-col output strip (64 vconv cols =
// 48 + 10 halo + 6 slack), streams its rows independently, and does the
// vconv->LDS->hconv handoff within the wave (same-wave LDS ordering, no
// s_barrier). ~30 independent wave-streams/CU -> phases overlap freely.
// Cost: vconv issued on 384 cols vs 256 (x1.2 VALU), +20% fetch. Bet:
// sum-of-pipes (42) collapses toward max-of-pipes (~24-28us).
//
// launch_bounds: one-arg only (R1/R3: any arg2 squeezing below natural
// VGPR spills 65-167MB).
__global__ __launch_bounds__(BLOCK) void ssim_wave_kernel(
    const float* __restrict__ img1, const float* __restrict__ img2,
    const float* __restrict__ window, float* __restrict__ out, float scale)
{
    // wave-private: res[wv][emit row 0..3][vconv col idx 0..63] (+2 pad).
    // idx i <-> image col OC*wv - 5 + i. 25.3 KB total.
    __shared__ v4f res[NW][4][66];
    __shared__ float red[NW];

    const float C1 = 1e-4f, C2 = 9e-4f;
    const int t = threadIdx.x;
    const int wv = t >> 6, ln = t & 63;
    const int band = blockIdx.x;     // 0..9 (band 9 partial: 22 rows)
    const int plane = blockIdx.y;    // 0..143
    const float* __restrict__ p1 = img1 + (size_t)plane * (Hd * Wd);
    const float* __restrict__ p2 = img2 + (size_t)plane * (Hd * Wd);

    // Separable 1D weights; pin to SGPRs.
    float wl[KW];
    {
        float c = sqrtf(window[5 * KW + 5]);
        #pragma unroll
        for (int k = 0; k < KW; ++k)
            wl[k] = rfl(window[k * KW + 5] / c);
    }

    const int ghbase = band * OUT_R - 5;       // global row of stream index 0
    const int vcol = OC * wv - 5 + ln;         // this lane's vconv column
    const bool colok = (unsigned)vcol < (unsigned)Wd;
    const int hr = ln >> 4, hq = ln & 15;      // hconv: row 0..3, quad (<12 active)

    v4f rng[16];                               // ring: (x, y, x2+y2, xy)
    float acc = 0.f;

    auto ssim_term = [&](v4f a) -> float {
        float mu1 = a.x, mu2 = a.y, sq = a.z, sp = a.w;
        float mu12 = mu1 * mu2;
        float musum = mu1 * mu1 + mu2 * mu2;
        float num = (2.f * mu12 + C1) * (2.f * (sp - mu12) + C2);
        float den = (musum + C1) * ((sq - musum) + C2);
        return num * __builtin_amdgcn_rcpf(den);
    };

    // initial 4-row load (stream rows 0..3); 1-deep prefetch thereafter
    float cx[4], cy[4];
    #pragma unroll
    for (int c = 0; c < 4; ++c) {
        int g = ghbase + c;
        bool ok = colok && (unsigned)g < (unsigned)Hd;
        int idx = (g << 8) + vcol;
        cx[c] = ok ? p1[idx] : 0.f;
        cy[c] = ok ? p2[idx] : 0.f;
    }

#define SSIM_STEP(PH, K, DOLOAD, DOEMIT) do {                                  \
    _Pragma("unroll")                                                          \
    for (int c = 0; c < 4; ++c) {          /* insert rows 4K..4K+3 */          \
        v4f e;                                                                 \
        e.x = cx[c]; e.y = cy[c];                                              \
        e.z = fmaf(cx[c], cx[c], cy[c] * cy[c]);                               \
        e.w = cx[c] * cy[c];                                                   \
        rng[4 * (PH) + c] = e;                                                 \
    }                                                                          \
    if (DOLOAD) {                          /* prefetch rows 4(K+1).. */        \
        _Pragma("unroll")                                                      \
        for (int c = 0; c < 4; ++c) {                                          \
            int g = ghbase + 4 * ((K) + 1) + c;                                \
            bool ok = colok && (unsigned)g < (unsigned)Hd;                     \
            int idx = (g << 8) + vcol;                                         \
            cx[c] = ok ? p1[idx] : 0.f;                                        \
            cy[c] = ok ? p2[idx] : 0.f;                                        \
        }                                                                      \
    }                                                                          \
    if (DOEMIT) {                                                              \
        _Pragma("unroll")                                                      \
        for (int c = 0; c < 4; ++c) {      /* vertical 11-tap, 4 rows */       \
            v4f a = {0.f, 0.f, 0.f, 0.f};                                      \
            _Pragma("unroll")                                                  \
            for (int m = 0; m < KW; ++m)                                       \
                a += wl[m] * rng[(4 * (PH) + 4 + c + m) & 15];                 \
            res[wv][c][ln] = a;            /* wave-private write */            \
        }                                                                      \
        /* same-wave LDS handoff: per-wave ds ordering, no barrier */          \
        {                                                                      \
            const int rr = 4 * (K) - 12 + hr;   /* band row of group hr */     \
            if (hq < 12 && rr < OUT_R && band * OUT_R + rr < Hd) {             \
                v4f a0 = {0.f, 0.f, 0.f, 0.f}, a1 = {0.f, 0.f, 0.f, 0.f};      \
                v4f a2 = {0.f, 0.f, 0.f, 0.f}, a3 = {0.f, 0.f, 0.f, 0.f};      \
                const v4f* b = &res[wv][hr][4 * hq];                           \
                _Pragma("unroll")                                              \
                for (int m = 0; m < 14; ++m) {  /* out cols OC*wv+4hq+j */     \
                    v4f v = b[m];                                              \
                    if (m <= 10)            a0 += wl[m] * v;                   \
                    if (m >= 1 && m <= 11)  a1 += wl[m - 1] * v;               \
                    if (m >= 2 && m <= 12)  a2 += wl[m - 2] * v;               \
                    if (m >= 3)             a3 += wl[m - 3] * v;               \
                }                                                              \
                const int ocol = OC * wv + 4 * hq;                             \
                if (ocol + 0 < Wd) acc += ssim_term(a0);                       \
                if (ocol + 1 < Wd) acc += ssim_term(a1);                       \
                if (ocol + 2 < Wd) acc += ssim_term(a2);                       \
                if (ocol + 3 < Wd) acc += ssim_term(a3);                       \
            }                                                                  \
        }                                                                      \
    }                                                                          \
} while (0)

    #pragma unroll 1
    for (int kb = 0; kb < 2; ++kb) {       // k = 0..7; phase = kk (static)
        #pragma unroll
        for (int kk = 0; kk < 4; ++kk) {
            SSIM_STEP(kk, 4 * kb + kk, true, (4 * kb + kk) >= 3);
        }
    }
    SSIM_STEP(0, 8, false, true);          // k=8: insert rows 32..35, emit 20..23
    #pragma unroll
    for (int c = 0; c < 4; ++c) { cx[c] = 0.f; cy[c] = 0.f; }
    SSIM_STEP(1, 9, false, true);          // epilogue: zero rows, emit 24..25

#undef SSIM_STEP

    // --- block reduction + fused global reduce (atomic); ONLY barrier ---
    #pragma unroll
    for (int off = 32; off > 0; off >>= 1)
        acc += __shfl_down(acc, off, 64);
    if (ln == 0) red[wv] = acc;
    __syncthreads();
    if (t == 0) {
        float partial = 0.f;
        #pragma unroll
        for (int i = 0; i < NW; ++i) partial += red[i];
        float v = partial * scale;                 // scale = -1/count
        if (band == 0 && plane == 0) v += 1.0f;    // out = 1 - sum/count
        atomicAdd(out, v);
    }
}

extern "C" void kernel_launch(void* const* d_in, const int* in_sizes, int n_in,
                              void* d_out, int out_size, void* d_ws, size_t ws_size,
                              hipStream_t stream) {
    const float* img1   = (const float*)d_in[0];
    const float* img2   = (const float*)d_in[1];
    const float* window = (const float*)d_in[2];
    float* out = (float*)d_out;

    const int planes = 16 * 9;                     // 144
    const int bands = (Hd + OUT_R - 1) / OUT_R;    // 10 (last band 22 rows)

    hipMemsetAsync(out, 0, sizeof(float), stream);

    const float scale = -(float)(1.0 / ((double)planes * Hd * Wd));
    dim3 grid(bands, planes);
    ssim_wave_kernel<<<grid, BLOCK, 0, stream>>>(img1, img2, window, out, scale);
}

// Round 11
// 121.861 us; speedup vs baseline: 1.3033x; 1.3033x over previous
//
#include <hip/hip_runtime.h>
#include <math.h>

#define Wd 256
#define Hd 256
#define KW 11
#define OUT_R 26              // output rows per block; stream 36 = 3 chunks of 12
#define RING 12               // ring size 12: slot=(2*jp+c)%12, chunk-independent
#define BLOCK 256

typedef float v2f __attribute__((ext_vector_type(2)));

__device__ __forceinline__ float rfl(float v) {
    return __int_as_float(__builtin_amdgcn_readfirstlane(__float_as_int(v)));
}

// lgkmcnt-only barrier (R2/R5): LDS handoff without draining global prefetch.
__device__ __forceinline__ void barrier_lds_only() {
    asm volatile("s_waitcnt lgkmcnt(0)\n\ts_barrier" ::: "memory");
}

// R11: R5 kernel (best measured: 42.2us dispatch) with ONE change: the
// final same-address atomicAdd is replaced by a per-block partial store to
// d_ws + a tiny reduce kernel.
//
// Why: 11-round invariance ledger (~42us) -- barrier flavor (R2), residency
// (R4), prefetch depth (R5 -4%), skew (R6), step size/LDS layout (R7),
// bank conflicts (no effect at 43K or 3M), memory residency (L3-resident ==
// HBM dispatch), instruction count (R9 pk_fma: fewer inst, SLOWER), wave
// privatization (R10: worse). The ONE untouched invariant: 1440 serialized
// same-address device-scope atomicAdds per dispatch. Same-address f32 RMW
// ping-pongs across 8 non-coherent XCD L2s at ~20-30ns each: 1440 x ~29ns
// ~= 42us == the invariant. Duration also tracked BLOCK COUNT (R4), not
// work. This round removes the contention entirely.
__global__ __launch_bounds__(BLOCK, 4) void ssim_pair_kernel(
    const float* __restrict__ img1, const float* __restrict__ img2,
    const float* __restrict__ window, float* __restrict__ ws)
{
    __shared__ __align__(16) float4 rbE[2][2][136];
    __shared__ __align__(16) float4 rbO[2][2][136];   // 17.4 KB
    __shared__ float red[BLOCK / 64];

    const float C1 = 1e-4f, C2 = 9e-4f;
    const int t = threadIdx.x;
    const int band = blockIdx.x;     // 0..9 (band 9 partial: 22 rows)
    const int plane = blockIdx.y;    // 0..143
    const float* __restrict__ p1 = img1 + (size_t)plane * (Hd * Wd);
    const float* __restrict__ p2 = img2 + (size_t)plane * (Hd * Wd);

    // Separable 1D weights (win2d = a outer a, sum a = 1); pin to SGPRs.
    float wl[KW];
    {
        float c = sqrtf(window[5 * KW + 5]);
        #pragma unroll
        for (int k = 0; k < KW; ++k)
            wl[k] = rfl(window[k * KW + 5] / c);
    }

    // Zero the column-halo cells once (never written by the row pass).
    if (t < 4) {
        int buf = t >> 1, row = t & 1;
        float4 z = make_float4(0.f, 0.f, 0.f, 0.f);
        rbE[buf][row][0] = z; rbE[buf][row][1] = z;
        rbE[buf][row][130] = z; rbE[buf][row][131] = z; rbE[buf][row][132] = z;
        rbO[buf][row][0] = z; rbO[buf][row][1] = z; rbO[buf][row][2] = z;
        rbO[buf][row][131] = z; rbO[buf][row][132] = z;
    }

    const int ghbase = band * OUT_R - 5;   // global row of stream index 0

    v2f rXY[RING], rQP[RING];
    float acc = 0.f;

    // 2-deep prefetch pipeline (R5): cur = this step's pair, nxt = next.
    float cx0, cy0, cx1, cy1;
    float nx0, ny0, nx1, ny1;
    {
        int g0 = ghbase, g1 = ghbase + 1;
        cx0 = ((unsigned)g0 < (unsigned)Hd) ? p1[(g0 << 8) + t] : 0.f;
        cy0 = ((unsigned)g0 < (unsigned)Hd) ? p2[(g0 << 8) + t] : 0.f;
        cx1 = ((unsigned)g1 < (unsigned)Hd) ? p1[(g1 << 8) + t] : 0.f;
        cy1 = ((unsigned)g1 < (unsigned)Hd) ? p2[(g1 << 8) + t] : 0.f;
        int g2 = ghbase + 2, g3 = ghbase + 3;
        nx0 = ((unsigned)g2 < (unsigned)Hd) ? p1[(g2 << 8) + t] : 0.f;
        ny0 = ((unsigned)g2 < (unsigned)Hd) ? p2[(g2 << 8) + t] : 0.f;
        nx1 = ((unsigned)g3 < (unsigned)Hd) ? p1[(g3 << 8) + t] : 0.f;
        ny1 = ((unsigned)g3 < (unsigned)Hd) ? p2[(g3 << 8) + t] : 0.f;
    }

    #pragma unroll 1
    for (int ch = 0; ch < 3; ++ch) {
        #pragma unroll
        for (int jp = 0; jp < 6; ++jp) {
            const int i0 = 12 * ch + 2 * jp;        // uniform (ch runtime)
            const int s0 = (2 * jp) % RING;         // STATIC slot
            const int s1 = (2 * jp + 1) % RING;     // STATIC slot

            // ring insert rows i0, i0+1 (consume cur; out-of-range = zeros)
            {
                v2f v; v.x = cx0; v.y = cy0; rXY[s0] = v;
                v2f q; q.x = fmaf(cx0, cx0, cy0 * cy0); q.y = cx0 * cy0; rQP[s0] = q;
                v2f v2; v2.x = cx1; v2.y = cy1; rXY[s1] = v2;
                v2f q2; q2.x = fmaf(cx1, cx1, cy1 * cy1); q2.y = cx1 * cy1; rQP[s1] = q2;
            }
            // rotate pipeline, issue loads 2 steps ahead
            cx0 = nx0; cy0 = ny0; cx1 = nx1; cy1 = ny1;
            if (i0 + 4 < 36) {
                int g0 = ghbase + i0 + 4, g1 = ghbase + i0 + 5;
                nx0 = ((unsigned)g0 < (unsigned)Hd) ? p1[(g0 << 8) + t] : 0.f;
                ny0 = ((unsigned)g0 < (unsigned)Hd) ? p2[(g0 << 8) + t] : 0.f;
                nx1 = ((unsigned)g1 < (unsigned)Hd) ? p1[(g1 << 8) + t] : 0.f;
                ny1 = ((unsigned)g1 < (unsigned)Hd) ? p2[(g1 << 8) + t] : 0.f;
            }

            const int orow0 = band * OUT_R + i0 - 10;     // uniform
            if (i0 >= 10 && orow0 < Hd) {   // emit rows i0, i0+1
                const int buf = jp & 1;
                v2f vAB0, vQP0, vAB1, vQP1;
                vAB0.x = vAB0.y = vQP0.x = vQP0.y = 0.f;
                vAB1.x = vAB1.y = vQP1.x = vQP1.y = 0.f;
                #pragma unroll
                for (int m = 0; m < KW; ++m) {
                    const int sa = (2 * jp + 2 + m) % RING;
                    const int sb = (2 * jp + 3 + m) % RING;
                    float w = wl[m];
                    vAB0 += w * rXY[sa];  vQP0 += w * rQP[sa];
                    vAB1 += w * rXY[sb];  vQP1 += w * rQP[sb];
                }
                const int half = t >> 1;
                if (t & 1) {
                    rbO[buf][0][half + 3] = make_float4(vAB0.x, vAB0.y, vQP0.x, vQP0.y);
                    rbO[buf][1][half + 3] = make_float4(vAB1.x, vAB1.y, vQP1.x, vQP1.y);
                } else {
                    rbE[buf][0][half + 2] = make_float4(vAB0.x, vAB0.y, vQP0.x, vQP0.y);
                    rbE[buf][1][half + 2] = make_float4(vAB1.x, vAB1.y, vQP1.x, vQP1.y);
                }
                barrier_lds_only();   // loads stay in flight

                const int r = t >> 7, cp = t & 127;   // output cols 2cp, 2cp+1
                const float4* bE = &rbE[buf][r][cp];
                const float4* bO = &rbO[buf][r][cp];
                v2f a0, q0, a1, q1;
                a0.x = a0.y = q0.x = q0.y = 0.f;
                a1.x = a1.y = q1.x = q1.y = 0.f;
                #pragma unroll
                for (int k = 0; k < 6; ++k) {
                    float4 vO = bO[k];                 // ds_read_b128
                    v2f oab; oab.x = vO.x; oab.y = vO.y;
                    v2f oqp; oqp.x = vO.z; oqp.y = vO.w;
                    a0 += wl[2 * k] * oab;  q0 += wl[2 * k] * oqp;
                    if (k >= 1) { a1 += wl[2 * k - 1] * oab;  q1 += wl[2 * k - 1] * oqp; }
                    float4 vE = bE[k];                 // ds_read_b128
                    v2f eab; eab.x = vE.x; eab.y = vE.y;
                    v2f eqp; eqp.x = vE.z; eqp.y = vE.w;
                    a1 += wl[2 * k] * eab;  q1 += wl[2 * k] * eqp;
                    if (k <= 4) { a0 += wl[2 * k + 1] * eab;  q0 += wl[2 * k + 1] * eqp; }
                }
                {
                    float mu1 = a0.x, mu2 = a0.y, sq = q0.x, sp = q0.y;
                    float mu1sq = mu1 * mu1, mu2sq = mu2 * mu2, mu12 = mu1 * mu2;
                    float musum = mu1sq + mu2sq;
                    float num = (2.f * mu12 + C1) * (2.f * (sp - mu12) + C2);
                    float den = (musum + C1) * ((sq - musum) + C2);
                    acc += num * __builtin_amdgcn_rcpf(den);
                }
                {
                    float mu1 = a1.x, mu2 = a1.y, sq = q1.x, sp = q1.y;
                    float mu1sq = mu1 * mu1, mu2sq = mu2 * mu2, mu12 = mu1 * mu2;
                    float musum = mu1sq + mu2sq;
                    float num = (2.f * mu12 + C1) * (2.f * (sp - mu12) + C2);
                    float den = (musum + C1) * ((sq - musum) + C2);
                    acc += num * __builtin_amdgcn_rcpf(den);
                }
            }
        }
    }

    // --- block reduction -> per-block partial in workspace (NO atomic) ---
    #pragma unroll
    for (int off = 32; off > 0; off >>= 1)
        acc += __shfl_down(acc, off, 64);
    int wave = t >> 6;
    if ((t & 63) == 0) red[wave] = acc;
    barrier_lds_only();
    if (t == 0)
        ws[blockIdx.y * gridDim.x + blockIdx.x] =
            red[0] + red[1] + red[2] + red[3];
}

// Tiny second pass: reduce the 1440 per-block partials, write the scalar.
__global__ __launch_bounds__(256) void ssim_reduce_kernel(
    const float* __restrict__ ws, float* __restrict__ out, float scale, int n)
{
    __shared__ float red[4];
    const int t = threadIdx.x;
    float s = 0.f;
    for (int i = t; i < n; i += 256) s += ws[i];
    #pragma unroll
    for (int off = 32; off > 0; off >>= 1)
        s += __shfl_down(s, off, 64);
    if ((t & 63) == 0) red[t >> 6] = s;
    __syncthreads();
    if (t == 0)
        out[0] = 1.0f + (red[0] + red[1] + red[2] + red[3]) * scale;
}

extern "C" void kernel_launch(void* const* d_in, const int* in_sizes, int n_in,
                              void* d_out, int out_size, void* d_ws, size_t ws_size,
                              hipStream_t stream) {
    const float* img1   = (const float*)d_in[0];
    const float* img2   = (const float*)d_in[1];
    const float* window = (const float*)d_in[2];
    float* out = (float*)d_out;
    float* ws  = (float*)d_ws;

    const int planes = 16 * 9;                     // 144
    const int bands = (Hd + OUT_R - 1) / OUT_R;    // 10 (last band 22 rows)
    const int nblocks = planes * bands;            // 1440 partials in d_ws

    const float scale = -(float)(1.0 / ((double)planes * Hd * Wd));
    dim3 grid(bands, planes);
    ssim_pair_kernel<<<grid, BLOCK, 0, stream>>>(img1, img2, window, ws);
    ssim_reduce_kernel<<<1, 256, 0, stream>>>(ws, out, scale, nblocks);
}